// Round 2
// baseline (958.812 us; speedup 1.0000x reference)
//
#include <hip/hip_runtime.h>

#define HW_T 1024
#define HW_S 4096

// ---------------------------------------------------------------------------
// Kernel 1: fused Q & K 1x1 conv.  Q[b][cq][hw] = sum_c qw[cq][c]*rgb[c][hw]+qb
// One thread per hw position; weights staged in LDS as float2 {qw, kw}.
// grid (16, 64): y -> (branch, batch); x*256 -> hw chunk (t exits x>=4).
// ---------------------------------------------------------------------------
__global__ __launch_bounds__(256)
void qk_kernel(const float* __restrict__ rgb_t, const float* __restrict__ rgb_s,
               const float* __restrict__ qw_t, const float* __restrict__ kw_t,
               const float* __restrict__ qw_s, const float* __restrict__ kw_s,
               const float* __restrict__ qb_t, const float* __restrict__ kb_t,
               const float* __restrict__ qb_s, const float* __restrict__ kb_s,
               float* __restrict__ Q_t, float* __restrict__ K_t,
               float* __restrict__ Q_s, float* __restrict__ K_s) {
    const int zb = blockIdx.y, br = zb >> 5, b = zb & 31;
    const int HW = br ? HW_S : HW_T;
    if ((int)blockIdx.x * 256 >= HW) return;   // whole-block uniform exit

    __shared__ float2 sWK[256 * 32];           // [c][cq] -> {qw, kw}, 64 KiB
    const float* qw = br ? qw_s : qw_t;
    const float* kw = br ? kw_s : kw_t;
    const int tid = threadIdx.x;
    for (int idx = tid; idx < 8192; idx += 256) {
        const int cq = idx >> 8, c = idx & 255;          // idx = cq*256 + c
        sWK[(c << 5) + cq] = make_float2(qw[idx], kw[idx]);
    }

    const float* qb = br ? qb_s : qb_t;
    const float* kb = br ? kb_s : kb_t;
    float qacc[32], kacc[32];
#pragma unroll
    for (int cq = 0; cq < 32; cq++) { qacc[cq] = qb[cq]; kacc[cq] = kb[cq]; }
    __syncthreads();

    const int hw = blockIdx.x * 256 + tid;
    const float* rgb = (br ? rgb_s : rgb_t) + (size_t)b * 256 * HW + hw;
#pragma unroll 2
    for (int c = 0; c < 256; c++) {
        const float r = rgb[(size_t)c * HW];
        const float2* wrow = &sWK[c << 5];
#pragma unroll
        for (int cq = 0; cq < 32; cq++) {
            const float2 w = wrow[cq];
            qacc[cq] = fmaf(r, w.x, qacc[cq]);
            kacc[cq] = fmaf(r, w.y, kacc[cq]);
        }
    }
    float* Q = (br ? Q_s : Q_t) + (size_t)b * 32 * HW + hw;
    float* K = (br ? K_s : K_t) + (size_t)b * 32 * HW + hw;
#pragma unroll
    for (int cq = 0; cq < 32; cq++) {
        Q[(size_t)cq * HW] = qacc[cq];
        K[(size_t)cq * HW] = kacc[cq];
    }
}

// ---------------------------------------------------------------------------
// Kernel 2: energy (Qr @ Kr^T over M) + reversed-softmax -> attn (fp32)
// Reshape quirk is a flat view: Qr[c][j] = Qflat[b][c*M + j], M = HW/8.
// softmax(max-E) == softmax(-E); stable via row-min: exp(min - E)/sum.
// Block: batch b, 32-row tile.  grid (8, 64).
// ---------------------------------------------------------------------------
__global__ __launch_bounds__(256)
void attn_kernel(const float* __restrict__ Q_t, const float* __restrict__ K_t,
                 const float* __restrict__ Q_s, const float* __restrict__ K_s,
                 float* __restrict__ A_t, float* __restrict__ A_s) {
    const int zb = blockIdx.y, br = zb >> 5, b = zb & 31;
    const int M = br ? (HW_S / 8) : (HW_T / 8);          // 512 / 128
    const float* Qb = (br ? Q_s : Q_t) + (size_t)b * 32 * (br ? HW_S : HW_T);
    const float* Kb = (br ? K_s : K_t) + (size_t)b * 32 * (br ? HW_S : HW_T);
    float* attn = (br ? A_s : A_t) + (size_t)b * 65536;
    const int c0 = blockIdx.x * 32;

    __shared__ float sK[256][33];
    __shared__ float sQ[32][33];
    __shared__ float eT[32][260];

    const int tid = threadIdx.x;
    const int dx = tid & 31, cy = tid >> 5;   // thread covers c = cy*4+i, d = dx+32j
    float acc[4][8] = {};

    for (int m0 = 0; m0 < M; m0 += 32) {
        __syncthreads();
        {
            const int rr = tid >> 3;
            const int cc = (tid & 7) << 2;
#pragma unroll
            for (int p = 0; p < 8; p++) {
                const int row = (p << 5) + rr;
                const float4 v = *(const float4*)(Kb + (size_t)row * M + m0 + cc);
                sK[row][cc] = v.x; sK[row][cc + 1] = v.y;
                sK[row][cc + 2] = v.z; sK[row][cc + 3] = v.w;
            }
            const float4 qv = *(const float4*)(Qb + (size_t)(c0 + rr) * M + m0 + cc);
            sQ[rr][cc] = qv.x; sQ[rr][cc + 1] = qv.y;
            sQ[rr][cc + 2] = qv.z; sQ[rr][cc + 3] = qv.w;
        }
        __syncthreads();
#pragma unroll 2
        for (int m = 0; m < 32; m++) {
            float kv[8];
#pragma unroll
            for (int j = 0; j < 8; j++) kv[j] = sK[dx + (j << 5)][m];
#pragma unroll
            for (int i = 0; i < 4; i++) {
                const float qv = sQ[(cy << 2) + i][m];
#pragma unroll
                for (int j = 0; j < 8; j++) acc[i][j] = fmaf(qv, kv[j], acc[i][j]);
            }
        }
    }

#pragma unroll
    for (int i = 0; i < 4; i++)
#pragma unroll
        for (int j = 0; j < 8; j++)
            eT[(cy << 2) + i][dx + (j << 5)] = acc[i][j];
    __syncthreads();

    // softmax: 8 threads per row (consecutive lanes), 32 cols each (stride 8)
    const int r = tid >> 3, s8 = tid & 7;
    float p[32];
    float mn = 3.0e38f;
#pragma unroll
    for (int m = 0; m < 32; m++) { p[m] = eT[r][s8 + (m << 3)]; mn = fminf(mn, p[m]); }
    mn = fminf(mn, __shfl_xor(mn, 1));
    mn = fminf(mn, __shfl_xor(mn, 2));
    mn = fminf(mn, __shfl_xor(mn, 4));
    float sum = 0.f;
#pragma unroll
    for (int m = 0; m < 32; m++) { p[m] = __expf(mn - p[m]); sum += p[m]; }
    sum += __shfl_xor(sum, 1);
    sum += __shfl_xor(sum, 2);
    sum += __shfl_xor(sum, 4);
    const float rinv = 1.0f / sum;
#pragma unroll
    for (int m = 0; m < 32; m++) eT[r][s8 + (m << 3)] = p[m] * rinv;
    __syncthreads();

    for (int idx = tid; idx < 2048; idx += 256) {
        const int row = idx >> 6, c4 = (idx & 63) << 2;
        const float4 v = *(const float4*)&eT[row][c4];
        *(float4*)(attn + (size_t)(c0 + row) * 256 + c4) = v;
    }
}

// ---------------------------------------------------------------------------
// Kernel 3/5: tiled GEMM  C[c][n] = sum_k A[c][k] * B[k][n]
//   A: fp32 per-batch [256,256] in ws.  B: fp32 (vw shared, or z per batch).
//   FINAL=0: store fp32 W' tile.  FINAL=1: out = alpha*(acc + b'[c]) + z.
// 64x64 tile, 256 threads, 4x4 micro-tile.  grid (N/64, 4, 64).
// ---------------------------------------------------------------------------
template <int FINAL>
__global__ __launch_bounds__(256)
void gemm64(const float* __restrict__ A_t, const float* __restrict__ A_s,
            const float* __restrict__ B_t, const float* __restrict__ B_s,
            float* __restrict__ C_t, float* __restrict__ C_s,
            float* __restrict__ O_t, float* __restrict__ O_s,
            const float* __restrict__ bp_t, const float* __restrict__ bp_s,
            const float* __restrict__ alpha_p, const float* __restrict__ beta_p,
            int N_t, int N_s) {
    const int zb = blockIdx.z, br = zb >> 5, b = zb & 31;
    const int N = br ? N_s : N_t;
    const int n0 = blockIdx.x * 64;
    if (n0 >= N) return;                        // whole-block uniform exit
    const int c0 = blockIdx.y * 64;
    const float* A = (br ? A_s : A_t) + (size_t)b * 65536;
    const float* Bm = (br ? B_s : B_t);
    if (FINAL) Bm += (size_t)b * 256 * (size_t)N;

    __shared__ float sA[64][36];
    __shared__ float sB[32][68];

    const int tid = threadIdx.x;
    const int tx = tid & 15, ty = tid >> 4;
    float acc[4][4] = {};

    for (int k0 = 0; k0 < 256; k0 += 32) {
        __syncthreads();
        {   // stage A (64 rows x 32 k)
            const int rr = tid >> 3;
            const int cc = (tid & 7) << 2;
            const float* Ap = A + (size_t)(c0 + rr) * 256 + (k0 + cc);
            const float4 v0 = *(const float4*)Ap;
            const float4 v1 = *(const float4*)(Ap + 32 * 256);
            *(float4*)&sA[rr][cc] = v0;
            *(float4*)&sA[rr + 32][cc] = v1;
        }
        {   // stage B (32 k x 64 n)
            const int rr = tid >> 4;
            const int cc = (tid & 15) << 2;
            const float* Bp = Bm + (size_t)(k0 + rr) * N + (n0 + cc);
            const float4 v0 = *(const float4*)Bp;
            const float4 v1 = *(const float4*)(Bp + (size_t)16 * N);
            sB[rr][cc + 0] = v0.x; sB[rr][cc + 1] = v0.y;
            sB[rr][cc + 2] = v0.z; sB[rr][cc + 3] = v0.w;
            sB[rr + 16][cc + 0] = v1.x; sB[rr + 16][cc + 1] = v1.y;
            sB[rr + 16][cc + 2] = v1.z; sB[rr + 16][cc + 3] = v1.w;
        }
        __syncthreads();
#pragma unroll
        for (int k = 0; k < 32; k++) {
            const float4 b4 = *(const float4*)&sB[k][tx << 2];
            const float a0 = sA[(ty << 2) + 0][k];
            const float a1 = sA[(ty << 2) + 1][k];
            const float a2 = sA[(ty << 2) + 2][k];
            const float a3 = sA[(ty << 2) + 3][k];
            acc[0][0] = fmaf(a0, b4.x, acc[0][0]); acc[0][1] = fmaf(a0, b4.y, acc[0][1]);
            acc[0][2] = fmaf(a0, b4.z, acc[0][2]); acc[0][3] = fmaf(a0, b4.w, acc[0][3]);
            acc[1][0] = fmaf(a1, b4.x, acc[1][0]); acc[1][1] = fmaf(a1, b4.y, acc[1][1]);
            acc[1][2] = fmaf(a1, b4.z, acc[1][2]); acc[1][3] = fmaf(a1, b4.w, acc[1][3]);
            acc[2][0] = fmaf(a2, b4.x, acc[2][0]); acc[2][1] = fmaf(a2, b4.y, acc[2][1]);
            acc[2][2] = fmaf(a2, b4.z, acc[2][2]); acc[2][3] = fmaf(a2, b4.w, acc[2][3]);
            acc[3][0] = fmaf(a3, b4.x, acc[3][0]); acc[3][1] = fmaf(a3, b4.y, acc[3][1]);
            acc[3][2] = fmaf(a3, b4.z, acc[3][2]); acc[3][3] = fmaf(a3, b4.w, acc[3][3]);
        }
    }

    if (FINAL) {
        const float alpha = br ? beta_p[0] : alpha_p[0];
        const float* bp = (br ? bp_s : bp_t) + b * 256;
        float* O = (br ? O_s : O_t) + (size_t)b * 256 * (size_t)N;
#pragma unroll
        for (int i = 0; i < 4; i++) {
            const int c = c0 + (ty << 2) + i;
            const float bpv = bp[c];
            const size_t off = (size_t)c * N + n0 + (tx << 2);
            const float4 zv = *(const float4*)(Bm + off);   // Bm IS z (batch base)
            float4 ov;
            ov.x = fmaf(alpha, acc[i][0] + bpv, zv.x);
            ov.y = fmaf(alpha, acc[i][1] + bpv, zv.y);
            ov.z = fmaf(alpha, acc[i][2] + bpv, zv.z);
            ov.w = fmaf(alpha, acc[i][3] + bpv, zv.w);
            *(float4*)(O + off) = ov;
        }
    } else {
        float* Co = (br ? C_s : C_t) + (size_t)b * 65536;
#pragma unroll
        for (int i = 0; i < 4; i++) {
            const int c = c0 + (ty << 2) + i;
            const float4 v = make_float4(acc[i][0], acc[i][1], acc[i][2], acc[i][3]);
            *(float4*)(Co + (size_t)c * 256 + n0 + (tx << 2)) = v;
        }
    }
}

// ---------------------------------------------------------------------------
// Kernel 4: b'[b][c] = sum_d attn[b][c][d] * vb[d]   (GEMV; vb is tiny)
// One wave per row, float4 loads + shuffle reduce.  grid (64).
// ---------------------------------------------------------------------------
__global__ __launch_bounds__(256)
void bprime_kernel(const float* __restrict__ A_t, const float* __restrict__ A_s,
                   const float* __restrict__ vb_t, const float* __restrict__ vb_s,
                   float* __restrict__ bp_t, float* __restrict__ bp_s) {
    const int bx = blockIdx.x, br = bx >> 5, b = bx & 31;
    const float* A = (br ? A_s : A_t) + (size_t)b * 65536;
    const float* vb = br ? vb_s : vb_t;
    float* bp = (br ? bp_s : bp_t) + b * 256;
    __shared__ float svb[256];
    svb[threadIdx.x] = vb[threadIdx.x];
    __syncthreads();
    const int wave = threadIdx.x >> 6, lane = threadIdx.x & 63;
    for (int c = wave; c < 256; c += 4) {
        const float4 a = *(const float4*)(A + (size_t)c * 256 + (lane << 2));
        const int l4 = lane << 2;
        float s = a.x * svb[l4] + a.y * svb[l4 + 1] + a.z * svb[l4 + 2] + a.w * svb[l4 + 3];
#pragma unroll
        for (int off = 32; off > 0; off >>= 1) s += __shfl_down(s, off);
        if (lane == 0) bp[c] = s;
    }
}

// ---------------------------------------------------------------------------
extern "C" void kernel_launch(void* const* d_in, const int* in_sizes, int n_in,
                              void* d_out, int out_size, void* d_ws, size_t ws_size,
                              hipStream_t stream) {
    const float* rgb_t = (const float*)d_in[0];
    const float* rgb_s = (const float*)d_in[1];
    const float* z_t   = (const float*)d_in[2];
    const float* z_s   = (const float*)d_in[3];
    const float* tq_w  = (const float*)d_in[4];
    const float* tq_b  = (const float*)d_in[5];
    const float* tk_w  = (const float*)d_in[6];
    const float* tk_b  = (const float*)d_in[7];
    const float* tv_w  = (const float*)d_in[8];
    const float* tv_b  = (const float*)d_in[9];
    const float* sq_w  = (const float*)d_in[10];
    const float* sq_b  = (const float*)d_in[11];
    const float* sk_w  = (const float*)d_in[12];
    const float* sk_b  = (const float*)d_in[13];
    const float* sv_w  = (const float*)d_in[14];
    const float* sv_b  = (const float*)d_in[15];
    const float* alpha = (const float*)d_in[16];
    const float* beta  = (const float*)d_in[17];

    // workspace layout (fp32).  W' aliases the Q/K region (attn is the last
    // reader of Q/K; gemm64<0> runs after attn_kernel).  Total ~58.8 MB.
    float* ws  = (float*)d_ws;
    float* At  = ws;                       // 32*256*256   attn (t)
    float* As_ = At + 2097152;             // attn (s)
    float* bt  = As_ + 2097152;            // 32*256 b' (t)
    float* bs  = bt + 8192;                // b' (s)
    float* Qt  = bs + 8192;                // 32*32*1024
    float* Kt  = Qt + 1048576;
    float* Qs  = Kt + 1048576;             // 32*32*4096
    float* Ks  = Qs + 4194304;
    float* Wt  = Qt;                       // alias: W' (t) over Qt/Kt
    float* Ws_ = Qs;                       // alias: W' (s) over Qs

    float* out_t = (float*)d_out;
    float* out_s = out_t + (size_t)32 * 256 * HW_T;   // 8,388,608 elements

    qk_kernel<<<dim3(16, 64), 256, 0, stream>>>(
        rgb_t, rgb_s, tq_w, tk_w, sq_w, sk_w,
        tq_b, tk_b, sq_b, sk_b, Qt, Kt, Qs, Ks);

    attn_kernel<<<dim3(8, 64), 256, 0, stream>>>(Qt, Kt, Qs, Ks, At, As_);

    bprime_kernel<<<dim3(64), 256, 0, stream>>>(At, As_, tv_b, sv_b, bt, bs);

    gemm64<0><<<dim3(4, 4, 64), 256, 0, stream>>>(
        At, As_, tv_w, sv_w, Wt, Ws_,
        (float*)nullptr, (float*)nullptr, (const float*)nullptr, (const float*)nullptr,
        (const float*)nullptr, (const float*)nullptr, 256, 256);

    gemm64<1><<<dim3(64, 4, 64), 256, 0, stream>>>(
        Wt, Ws_, z_t, z_s, (float*)nullptr, (float*)nullptr,
        out_t, out_s, bt, bs, alpha, beta, HW_T, HW_S);
}